// Round 1
// 178.224 us; speedup vs baseline: 1.0149x; 1.0149x over previous
//
#include <hip/hip_runtime.h>
#include <hip/hip_bf16.h>

// FlowNetC correlation: B=4, C=256, H=W=96, PAD=MAX_DISP=20, STRIDE2=2, D=21.
// out[b, oy*21+ox, h, w] = (1/C) * sum_c x1[b,c,h,w] * x2[b,c,h+2oy-20,w+2ox-20]
//
// dx even -> split w by parity. Per (b,h,oy,par): out[i,e] = sum_c A[c,i]*B[c,i+e-10]
// (i=w>>1 in [0,48), e=ox). Band GEMM, MFMA 16x16x32 bf16.
//
// corr block = (b, h, oy-half): A fragments live in registers across the oy loop;
// x2[b,h2] images (48KB each) DMA'd to LDS via global_load_lds, TRIPLE-buffered
// with a 2-deep prefetch pipeline and counted s_waitcnt vmcnt(N) + raw s_barrier
// (never vmcnt(0) in steady state) so DMA of oy+1/oy+2 flies under compute+store
// of oy. Global layout is XOR-swizzled per row (chunk' = chunk ^ (row&31)) so
// fragment ds_read_b128 at 512B row stride is bank-conflict-free.
//
// vmcnt ledger (per wave, in issue order):  P = 8 gl2lds per image prefetch,
// S = 5..6 epilogue stores per oy (>=5 guaranteed: 2016 elems / 384 thr).
// At iter k we need P(k) [issued at iter k-2 / prologue] retired. Ops issued
// after P(k): >= S(k-2) + P(k+1) + S(k-1) + P(k+2) >= 26 in steady state, so
// vmcnt(21) retires P(k) (in-order retirement, m135). Edges: k==0 -> 16/8/0
// (only P1[,P2] newer); k==nv-2 -> 13; k==nv-1 -> 5. Valid-oy range is
// contiguous; OOB oy zero-filled in a pre-pass so the ledger stays uniform.

typedef __bf16 bf16x8 __attribute__((ext_vector_type(8)));
typedef float f32x4 __attribute__((ext_vector_type(4)));

#define B_ 4
#define C_ 256
#define H_ 96
#define W_ 96
#define NOFF 21
#define ROWS 96                         // rows per (b,h) image = 2 par * 48
#define IMG_ELEMS (ROWS * C_)           // 24576 ushorts = 48KB
#define IMG_BYTES (IMG_ELEMS * 2)       // 49152
#define X1T_ELEMS (B_ * H_ * IMG_ELEMS) // 9,437,184 ushorts

__device__ __forceinline__ unsigned short f32_to_bf16_rne(float f) {
    union { float f; unsigned u; } v; v.f = f;
    unsigned u = v.u;
    return (unsigned short)((u + 0x7fffu + ((u >> 16) & 1u)) >> 16);
}

__device__ __forceinline__ void gl2lds16(const void* g, void* l) {
    __builtin_amdgcn_global_load_lds(
        (const __attribute__((address_space(1))) void*)g,
        (__attribute__((address_space(3))) void*)l, 16, 0, 0);
}

// ---------------------------------------------------------------------------
// Prep: fp32 NCHW -> bf16 swizzled-transposed [b][h][row][chunk^(row&31)]
// row = par*48 + (w>>1), par = w&1. One block per (b,h,src,c-block-of-64).
// ---------------------------------------------------------------------------
__global__ __launch_bounds__(256) void prep_kernel(const float* __restrict__ x1,
                                                   const float* __restrict__ x2,
                                                   unsigned short* __restrict__ ws) {
    __shared__ float tile[96 * 65];   // [w][c_local], pitch 65: conflict-free
    int bid = blockIdx.x;
    int cblk  = bid & 3;
    int which = (bid >> 2) & 1;
    int bh    = bid >> 3;             // 0..383
    int h = bh % H_;
    int b = bh / H_;
    int c0 = cblk << 6;

    const float* src = (which ? x2 : x1) + ((size_t)(b * C_ + c0) * H_ + h) * W_;
    unsigned short* dst = ws + (size_t)which * X1T_ELEMS + (size_t)(b * H_ + h) * IMG_ELEMS;

    // Phase A: coalesced global reads -> LDS [w][c]
    for (int idx = threadIdx.x; idx < 64 * 96; idx += 256) {
        int c = idx / 96, w = idx - c * 96;
        tile[w * 65 + c] = src[c * (H_ * W_) + w];
    }
    __syncthreads();

    // Phase B: pack 8 c -> 16B store. Per row this c-block lands in one
    // contiguous 128B run (aligned 8-chunk group XOR'd by row bits). Dest-driven.
    for (int idx = threadIdx.x; idx < 96 * 8; idx += 256) {
        int row = idx >> 3, tp = idx & 7;
        int par = row / 48, i = row - par * 48;
        int w = 2 * i + par;
        int s = tp ^ (row & 7);                 // source chunk within c-block
        const float* fsrc = &tile[w * 65 + (s << 3)];
        unsigned pk[4];
#pragma unroll
        for (int e = 0; e < 4; ++e) {
            unsigned lo = f32_to_bf16_rne(fsrc[2 * e]);
            unsigned hi = f32_to_bf16_rne(fsrc[2 * e + 1]);
            pk[e] = lo | (hi << 16);
        }
        int ccp = (((c0 >> 3) ^ (row & 24)) + tp);   // swizzled chunk position
        *(uint4*)((char*)(dst + (size_t)row * C_) + (ccp << 4)) =
            make_uint4(pk[0], pk[1], pk[2], pk[3]);
    }
}

// ---------------------------------------------------------------------------
// Main: block = (b, h, og). 6 waves = (par, mt). oy pipeline over valid range.
// ---------------------------------------------------------------------------
__global__ __launch_bounds__(384, 1) void corr_kernel(const unsigned short* __restrict__ ws,
                                                      float* __restrict__ out) {
    __shared__ unsigned short Bs[3][IMG_ELEMS];   // 3 x 48KB, pipeline ring
    __shared__ float sl[NOFF][97];                // epilogue transpose slab
    static_assert(sizeof(Bs) + sizeof(sl) <= 163840, "LDS budget");

    int bid = blockIdx.x;
    int xcd = bid & 7, sidx = bid >> 3;        // XCD-aware: each XCD gets (b, h-half)
    int b  = xcd >> 1;
    int h  = ((xcd & 1) ? 48 : 0) + (sidx >> 1);
    int og = sidx & 1;

    int tid = threadIdx.x;
    int wv = tid >> 6, lane = tid & 63;
    int par = wv & 1, mt = wv >> 1;
    int i0 = mt << 4;
    int n = lane & 15, quad = lane >> 4;

    // A fragments: loaded once from global, reused for all oy.
    int rowA = par * 48 + i0 + n;
    const unsigned short* Ag = ws + (size_t)(b * H_ + h) * IMG_ELEMS + (size_t)rowA * C_;
    int keyA = rowA & 31;
    bf16x8 afrag[8];
#pragma unroll
    for (int ks = 0; ks < 8; ++ks)
        afrag[ks] = *(const bf16x8*)(Ag + ((((ks << 2) | quad) ^ keyA) << 3));

    const unsigned short* Bimg = ws + (size_t)X1T_ELEMS + (size_t)(b * H_) * IMG_ELEMS;

    int rowB0 = par * 48 + n;          // u=0 (j 0..15)
    int rowB1 = rowB0 + 16;            // u=1 (j 16..31)
    int rowB2 = rowB0 + 32;            // u=2 (j 32..47)
    int keyB0 = rowB0 & 31, keyB1 = rowB1 & 31, keyB2 = rowB2 & 31;

    int oy_lo = og ? 11 : 0;
    int oy_hi = og ? NOFF : 11;

    // Valid oy band (contiguous): 0 <= h + 2*oy - 20 < 96.
    int vlo = oy_lo, vhi = oy_hi;
    {
        int lo = (h <= 20) ? ((21 - h) >> 1) : 0;   // ceil((20-h)/2)
        int hi = ((115 - h) >> 1) + 1;              // one past last valid
        if (lo > vlo) vlo = lo;
        if (hi < vhi) vhi = hi;
    }
    int nv = vhi - vlo; if (nv < 0) nv = 0;

    int wvoff  = wv * 8192;            // wave-uniform LDS base offset
    int gmaoff = wvoff + lane * 16;    // per-lane global offset

    // Prologue prefetch: first two valid images (P(0), P(1)).
    if (nv > 0) {
        const char* Bg = (const char*)(Bimg + (size_t)(h + 2 * vlo - 20) * IMG_ELEMS);
#pragma unroll
        for (int c = 0; c < 8; ++c)
            gl2lds16(Bg + gmaoff + c * 1024, (char*)Bs[0] + wvoff + c * 1024);
    }
    if (nv > 1) {
        const char* Bg = (const char*)(Bimg + (size_t)(h + 2 * (vlo + 1) - 20) * IMG_ELEMS);
#pragma unroll
        for (int c = 0; c < 8; ++c)
            gl2lds16(Bg + gmaoff + c * 1024, (char*)Bs[1] + wvoff + c * 1024);
    }

    // Zero-fill out-of-range oy outputs (overlaps with prologue DMA in flight).
    for (int oy = oy_lo; oy < oy_hi; ++oy) {
        if (oy >= vlo && oy < vhi) continue;
        int outb = ((b * 441 + oy * NOFF) * H_ + h) * W_;
        for (int idx = tid; idx < NOFF * W_; idx += 384)
            out[outb + (idx / W_) * (H_ * W_) + (idx % W_)] = 0.0f;
    }

    // Pipelined main loop over the valid band.
    for (int k = 0; k < nv; ++k) {
        int oy = vlo + k;
        int cur = k % 3;

        // (a) prefetch image for oy+2 into ring slot (k+2)%3. Safe: that slot
        // was last ds_read at iter k-1, all waves past the (e) barrier since.
        if (k + 2 < nv) {
            int nb = (k + 2) % 3;
            const char* Bg = (const char*)(Bimg + (size_t)(h + 2 * (oy + 2) - 20) * IMG_ELEMS);
#pragma unroll
            for (int c = 0; c < 8; ++c)
                gl2lds16(Bg + gmaoff + c * 1024, (char*)Bs[nb] + wvoff + c * 1024);
        }

        // (b) counted wait for P(k) retirement + barrier (all waves' DMA landed).
        if (k == 0) {
            if (nv > 2)       asm volatile("s_waitcnt vmcnt(16)\ns_barrier" ::: "memory");
            else if (nv == 2) asm volatile("s_waitcnt vmcnt(8)\ns_barrier" ::: "memory");
            else              asm volatile("s_waitcnt vmcnt(0)\ns_barrier" ::: "memory");
        } else if (k + 2 < nv) {
            asm volatile("s_waitcnt vmcnt(21)\ns_barrier" ::: "memory");
        } else if (k + 1 < nv) {
            asm volatile("s_waitcnt vmcnt(13)\ns_barrier" ::: "memory");
        } else {
            asm volatile("s_waitcnt vmcnt(5)\ns_barrier" ::: "memory");
        }

        // (d) compute from ring slot cur.
        f32x4 acc0 = {0.f,0.f,0.f,0.f}, acc1 = {0.f,0.f,0.f,0.f}, acc2 = {0.f,0.f,0.f,0.f};
        const char* Bsb = (const char*)Bs[cur];
        // valid B tiles per M-tile: mt0:{u0,u1} mt1:{u0,u1,u2} mt2:{u1,u2}
        if (mt == 0) {
#pragma unroll
            for (int ks = 0; ks < 8; ++ks) {
                int ci = (ks << 2) | quad;
                bf16x8 b0 = *(const bf16x8*)(Bsb + rowB0 * 512 + ((ci ^ keyB0) << 4));
                bf16x8 b1 = *(const bf16x8*)(Bsb + rowB1 * 512 + ((ci ^ keyB1) << 4));
                acc0 = __builtin_amdgcn_mfma_f32_16x16x32_bf16(afrag[ks], b0, acc0, 0, 0, 0);
                acc1 = __builtin_amdgcn_mfma_f32_16x16x32_bf16(afrag[ks], b1, acc1, 0, 0, 0);
            }
        } else if (mt == 1) {
#pragma unroll
            for (int ks = 0; ks < 8; ++ks) {
                int ci = (ks << 2) | quad;
                bf16x8 b0 = *(const bf16x8*)(Bsb + rowB0 * 512 + ((ci ^ keyB0) << 4));
                bf16x8 b1 = *(const bf16x8*)(Bsb + rowB1 * 512 + ((ci ^ keyB1) << 4));
                bf16x8 b2 = *(const bf16x8*)(Bsb + rowB2 * 512 + ((ci ^ keyB2) << 4));
                acc0 = __builtin_amdgcn_mfma_f32_16x16x32_bf16(afrag[ks], b0, acc0, 0, 0, 0);
                acc1 = __builtin_amdgcn_mfma_f32_16x16x32_bf16(afrag[ks], b1, acc1, 0, 0, 0);
                acc2 = __builtin_amdgcn_mfma_f32_16x16x32_bf16(afrag[ks], b2, acc2, 0, 0, 0);
            }
        } else {
#pragma unroll
            for (int ks = 0; ks < 8; ++ks) {
                int ci = (ks << 2) | quad;
                bf16x8 b1 = *(const bf16x8*)(Bsb + rowB1 * 512 + ((ci ^ keyB1) << 4));
                bf16x8 b2 = *(const bf16x8*)(Bsb + rowB2 * 512 + ((ci ^ keyB2) << 4));
                acc1 = __builtin_amdgcn_mfma_f32_16x16x32_bf16(afrag[ks], b1, acc1, 0, 0, 0);
                acc2 = __builtin_amdgcn_mfma_f32_16x16x32_bf16(afrag[ks], b2, acc2, 0, 0, 0);
            }
        }

        // Scatter valid band entries. C/D: col n = lane&15, row m = quad*4+r.
        // ox = 16*(u+1) + n - (i0+m) - 6.
#pragma unroll
        for (int r = 0; r < 4; ++r) {
            int m = (quad << 2) + r;
            int w = 2 * (i0 + m) + par;
            int oxb = n - i0 - m - 6;
            if (mt != 2) { int ox = 16 + oxb; if (ox >= 0 && ox < NOFF) sl[ox][w] = acc0[r]; }
            {             int ox = 32 + oxb; if (ox >= 0 && ox < NOFF) sl[ox][w] = acc1[r]; }
            if (mt != 0) { int ox = 48 + oxb; if (ox >= 0 && ox < NOFF) sl[ox][w] = acc2[r]; }
        }

        // (e) LDS drain + barrier: sl scatter visible; all waves done reading
        // Bs[cur] (so iter k+1's prefetch may overwrite slot (k+3)%3 == cur).
        asm volatile("s_waitcnt lgkmcnt(0)\ns_barrier" ::: "memory");

        // (f) store: stale slab entries are exactly the out-of-range ones.
        // Every wave issues >=5 stores here — required by the vmcnt ledger.
        int outb = ((b * 441 + oy * NOFF) * H_ + h) * W_;
        for (int idx = tid; idx < NOFF * W_; idx += 384) {
            int ox = idx / W_, w = idx - ox * W_;
            int w2 = w + 2 * ox - 20;
            float v = (w2 >= 0 && w2 < W_) ? sl[ox][w] * (1.0f / 256.0f) : 0.0f;
            out[outb + ox * (H_ * W_) + w] = v;
        }
    }
}

// ---------------------------------------------------------------------------
// Fallback (ws too small): direct fp32, slow but correct.
// ---------------------------------------------------------------------------
__global__ __launch_bounds__(256) void corr_fallback(const float* __restrict__ x1,
                                                     const float* __restrict__ x2,
                                                     float* __restrict__ out) {
    int bid = blockIdx.x;
    int oy = bid % NOFF, h = (bid / NOFF) % H_, b = bid / (NOFF * H_);
    int dy = 2 * oy - 20, h2 = h + dy;
    int outbase = ((b * 441 + oy * NOFF) * H_ + h) * W_;
    for (int idx = threadIdx.x; idx < NOFF * W_; idx += 256) {
        int ox = idx / W_, w = idx % W_;
        float acc = 0.f;
        int w2 = w + 2 * ox - 20;
        if (h2 >= 0 && h2 < H_ && w2 >= 0 && w2 < W_) {
            const float* p1 = x1 + (size_t)b * C_ * H_ * W_ + h * W_ + w;
            const float* p2 = x2 + (size_t)b * C_ * H_ * W_ + h2 * W_ + w2;
            for (int c = 0; c < C_; ++c) acc += p1[c * (H_ * W_)] * p2[c * (H_ * W_)];
        }
        out[outbase + ox * (H_ * W_) + w] = acc * (1.0f / 256.0f);
    }
}

extern "C" void kernel_launch(void* const* d_in, const int* in_sizes, int n_in,
                              void* d_out, int out_size, void* d_ws, size_t ws_size,
                              hipStream_t stream) {
    const float* x1 = (const float*)d_in[0];
    const float* x2 = (const float*)d_in[1];
    float* out = (float*)d_out;

    size_t need = (size_t)2 * X1T_ELEMS * sizeof(unsigned short);  // 37.7 MB
    if (ws_size >= need) {
        unsigned short* ws = (unsigned short*)d_ws;
        prep_kernel<<<B_ * H_ * 2 * 4, 256, 0, stream>>>(x1, x2, ws);
        corr_kernel<<<768, 384, 0, stream>>>(ws, out);
    } else {
        corr_fallback<<<B_ * H_ * NOFF, 256, 0, stream>>>(x1, x2, out);
    }
}

// Round 2
// 164.636 us; speedup vs baseline: 1.0987x; 1.0825x over previous
//
#include <hip/hip_runtime.h>
#include <hip/hip_bf16.h>

// FlowNetC correlation: B=4, C=256, H=W=96, PAD=MAX_DISP=20, STRIDE2=2, D=21.
// out[b, oy*21+ox, h, w] = (1/C) * sum_c x1[b,c,h,w] * x2[b,c,h+2oy-20,w+2ox-20]
//
// dx even -> split w by parity. Per (b,h,oy,par): out[i,e] = sum_c A[c,i]*B[c,i+e-10]
// (i=w>>1 in [0,48), e=ox). Band GEMM, MFMA 16x16x32 bf16.
//
// h-PAIRING: (h, oy=t) and (h+2, oy=t-1) share image x2[b, h+2t-20]. A block owns
// rows {hA, hA+2} and one oy-quarter; per image t it computes BOTH output planes:
// 2x MFMA per B-fragment ds_read, 1 image DMA + 2 barriers per 2 planes.
// A fragments for both rows live in registers across the t loop; x2 images
// triple-buffered in LDS via global_load_lds with counted s_waitcnt vmcnt(N)
// + raw s_barrier (never vmcnt(0) in steady state). Global layout is
// XOR-swizzled per row (chunk' = chunk ^ (row&31)) so ds_read_b128 at 512B row
// stride is bank-conflict-free.
//
// vmcnt ledger (per wave, issue order): P = 8 gl2lds per image, S = epilogue
// stores per iter (>=5 guaranteed: >=1 valid plane, 2016 elems / 384 thr).
// At iter k, P(k) was issued at iter k-2 (or prologue); ops after it:
// >= S(k-2)+P(k+1)+S(k-1)+P(k+2) >= 26 steady -> vmcnt(21). Edges: k==0 ->
// 16/8/0 (P1[,P2] newer); k==nv-2 -> 13; k==nv-1 -> 5. asm "memory" fences at
// every phase boundary keep the issue-order windows; gl2lds intrinsics are
// side-effecting and never reorder among themselves.
//
// Latency fixes vs prior version (the real 5800cyc/iter cost): B-fragments
// batch-loaded into unrolled register arrays (all reads in flight before the
// MFMA burst); epilogue addressing (ox,w,slot,off,mask) hoisted to prologue;
// slab reads batched then stored (no rolled div/mod + serial ds_read chain).

typedef __bf16 bf16x8 __attribute__((ext_vector_type(8)));
typedef float f32x4 __attribute__((ext_vector_type(4)));

#define B_ 4
#define C_ 256
#define H_ 96
#define W_ 96
#define NOFF 21
#define ROWS 96                         // rows per (b,h) image = 2 par * 48
#define IMG_ELEMS (ROWS * C_)           // 24576 ushorts = 48KB
#define X1T_ELEMS (B_ * H_ * IMG_ELEMS) // 9,437,184 ushorts

__device__ __forceinline__ unsigned short f32_to_bf16_rne(float f) {
    union { float f; unsigned u; } v; v.f = f;
    unsigned u = v.u;
    return (unsigned short)((u + 0x7fffu + ((u >> 16) & 1u)) >> 16);
}

__device__ __forceinline__ void gl2lds16(const void* g, void* l) {
    __builtin_amdgcn_global_load_lds(
        (const __attribute__((address_space(1))) void*)g,
        (__attribute__((address_space(3))) void*)l, 16, 0, 0);
}

// ---------------------------------------------------------------------------
// Prep: fp32 NCHW -> bf16 swizzled-transposed [b][h][row][chunk^(row&31)]
// row = par*48 + (w>>1), par = w&1. One block per (b,h,src,c-block-of-64).
// ---------------------------------------------------------------------------
__global__ __launch_bounds__(256) void prep_kernel(const float* __restrict__ x1,
                                                   const float* __restrict__ x2,
                                                   unsigned short* __restrict__ ws) {
    __shared__ float tile[96 * 65];   // [w][c_local], pitch 65: conflict-free
    int bid = blockIdx.x;
    int cblk  = bid & 3;
    int which = (bid >> 2) & 1;
    int bh    = bid >> 3;             // 0..383
    int h = bh % H_;
    int b = bh / H_;
    int c0 = cblk << 6;

    const float* src = (which ? x2 : x1) + ((size_t)(b * C_ + c0) * H_ + h) * W_;
    unsigned short* dst = ws + (size_t)which * X1T_ELEMS + (size_t)(b * H_ + h) * IMG_ELEMS;

    // Phase A: coalesced global reads -> LDS [w][c]
    for (int idx = threadIdx.x; idx < 64 * 96; idx += 256) {
        int c = idx / 96, w = idx - c * 96;
        tile[w * 65 + c] = src[c * (H_ * W_) + w];
    }
    __syncthreads();

    // Phase B: pack 8 c -> 16B store. Per row this c-block lands in one
    // contiguous 128B run (aligned 8-chunk group XOR'd by row bits). Dest-driven.
    for (int idx = threadIdx.x; idx < 96 * 8; idx += 256) {
        int row = idx >> 3, tp = idx & 7;
        int par = row / 48, i = row - par * 48;
        int w = 2 * i + par;
        int s = tp ^ (row & 7);                 // source chunk within c-block
        const float* fsrc = &tile[w * 65 + (s << 3)];
        unsigned pk[4];
#pragma unroll
        for (int e = 0; e < 4; ++e) {
            unsigned lo = f32_to_bf16_rne(fsrc[2 * e]);
            unsigned hi = f32_to_bf16_rne(fsrc[2 * e + 1]);
            pk[e] = lo | (hi << 16);
        }
        int ccp = (((c0 >> 3) ^ (row & 24)) + tp);   // swizzled chunk position
        *(uint4*)((char*)(dst + (size_t)row * C_) + (ccp << 4)) =
            make_uint4(pk[0], pk[1], pk[2], pk[3]);
    }
}

// ---------------------------------------------------------------------------
// Main: block = (b, h-pair, oy-quarter). 6 waves = (par, mt).
// ---------------------------------------------------------------------------
__global__ __launch_bounds__(384, 2) void corr_kernel(const unsigned short* __restrict__ ws,
                                                      float* __restrict__ out) {
    __shared__ unsigned short Bs[3][IMG_ELEMS];   // 3 x 48KB, pipeline ring
    __shared__ float sl[2][NOFF][97];             // dual transpose slab (A,B rows)
    static_assert(sizeof(Bs) + sizeof(sl) <= 163840, "LDS budget");

    int bid = blockIdx.x;
    int xcd = bid & 7, sidx = bid >> 3;        // XCD-aware: each XCD gets (b, h-half)
    int b  = xcd >> 1;
    int p  = ((xcd & 1) ? 24 : 0) + (sidx >> 2);   // pair index [0,48)
    int og = sidx & 3;                              // oy quarter
    int g = p >> 1, par_h = p & 1;
    int hA = 4 * g + par_h, hB = hA + 2;            // {h mod4 in 0,1} x {+2}
    int olo = (og * NOFF) >> 2;                     // 0,5,10,15
    int ohi = ((og + 1) * NOFF) >> 2;               // 5,10,15,21

    int tid = threadIdx.x;
    int wv = tid >> 6, lane = tid & 63;
    int par = wv & 1, mt = wv >> 1;
    int i0 = mt << 4;
    int n = lane & 15, quad = lane >> 4;

    // Hoisted epilogue addressing: idx = tid + 384j, j < jcnt (5 or 6).
    int jcnt = 5 + (tid < 96 ? 1 : 0);
    int slotj[6], offj[6]; bool mj[6];
#pragma unroll
    for (int j = 0; j < 6; ++j) {
        int idx = tid + j * 384;
        int ox = idx / W_, w = idx - ox * W_;
        slotj[j] = ox * 97 + w;
        offj[j]  = ox * (H_ * W_) + w;
        int w2 = w + 2 * ox - 20;
        mj[j] = (w2 >= 0) & (w2 < W_);
    }

    // A fragments for BOTH rows: loaded once, reused for all t.
    int rowA = par * 48 + i0 + n;
    int keyA = rowA & 31;
    const unsigned short* AgA = ws + (size_t)(b * H_ + hA) * IMG_ELEMS + (size_t)rowA * C_;
    const unsigned short* AgB = ws + (size_t)(b * H_ + hB) * IMG_ELEMS + (size_t)rowA * C_;
    bf16x8 afA[8], afB[8];
#pragma unroll
    for (int ks = 0; ks < 8; ++ks) {
        int o = (((ks << 2) | quad) ^ keyA) << 3;
        afA[ks] = *(const bf16x8*)(AgA + o);
        afB[ks] = *(const bf16x8*)(AgB + o);
    }

    const unsigned short* Bimg = ws + (size_t)X1T_ELEMS + (size_t)(b * H_) * IMG_ELEMS;

    int rowB0 = par * 48 + n;          // u=0 (j 0..15)
    int rowB1 = rowB0 + 16;            // u=1
    int rowB2 = rowB0 + 32;            // u=2
    int keyB0 = rowB0 & 31, keyB1 = rowB1 & 31, keyB2 = rowB2 & 31;

    // Valid oy bands per row (clip h2 in range AND og quarter).
    int aLo = (hA <= 20) ? ((21 - hA) >> 1) : 0; if (aLo < olo) aLo = olo;
    int aHi = ((115 - hA) >> 1) + 1;             if (aHi > ohi) aHi = ohi;
    if (aHi < aLo) aHi = aLo;
    int bLo = (hB <= 20) ? ((21 - hB) >> 1) : 0; if (bLo < olo) bLo = olo;
    int bHi = ((115 - hB) >> 1) + 1;             if (bHi > ohi) bHi = ohi;
    if (bHi < bLo) bHi = bLo;

    // Image parameter t: planeA oy=t (t in [aLo,aHi)), planeB oy=t-1
    // (t in [bLo+1,bHi+1)). Union is contiguous (starts/ends differ by <=1).
    int tlo, thi;
    bool ea = (aLo >= aHi), eb = (bLo >= bHi);
    if (ea && eb)      { tlo = 0; thi = 0; }
    else if (ea)       { tlo = bLo + 1; thi = bHi + 1; }
    else if (eb)       { tlo = aLo; thi = aHi; }
    else {
        tlo = (aLo < bLo + 1) ? aLo : bLo + 1;
        thi = (aHi > bHi + 1) ? aHi : bHi + 1;
    }
    int nv = thi - tlo;

    int wvoff  = wv * 8192;            // wave-uniform LDS base offset
    int gmaoff = wvoff + lane * 16;    // per-lane global offset

    // Prologue prefetch: images t = tlo, tlo+1.
    if (nv > 0) {
        const char* Bg = (const char*)(Bimg + (size_t)(hA + 2 * tlo - 20) * IMG_ELEMS);
#pragma unroll
        for (int c = 0; c < 8; ++c)
            gl2lds16(Bg + gmaoff + c * 1024, (char*)Bs[0] + wvoff + c * 1024);
    }
    if (nv > 1) {
        const char* Bg = (const char*)(Bimg + (size_t)(hA + 2 * (tlo + 1) - 20) * IMG_ELEMS);
#pragma unroll
        for (int c = 0; c < 8; ++c)
            gl2lds16(Bg + gmaoff + c * 1024, (char*)Bs[1] + wvoff + c * 1024);
    }

    // Zero-fill out-of-band planes for both rows (overlaps prologue DMA).
    for (int oy = olo; oy < ohi; ++oy) {
        if (oy < aLo || oy >= aHi) {
            int outb = ((b * 441 + oy * NOFF) * H_ + hA) * W_;
#pragma unroll
            for (int j = 0; j < 6; ++j) if (j < jcnt) out[outb + offj[j]] = 0.0f;
        }
        if (oy < bLo || oy >= bHi) {
            int outb = ((b * 441 + oy * NOFF) * H_ + hB) * W_;
#pragma unroll
            for (int j = 0; j < 6; ++j) if (j < jcnt) out[outb + offj[j]] = 0.0f;
        }
    }

    const float* slA = &sl[0][0][0];
    const float* slB = &sl[1][0][0];

    for (int k = 0; k < nv; ++k) {
        int t = tlo + k;
        int cur = k % 3;

        // (a) prefetch image t+2 into slot (k+2)%3 (last read at iter k-1,
        // all waves past the (e) barrier since).
        if (k + 2 < nv) {
            int nb = (k + 2) % 3;
            const char* Bg = (const char*)(Bimg + (size_t)(hA + 2 * (t + 2) - 20) * IMG_ELEMS);
#pragma unroll
            for (int c = 0; c < 8; ++c)
                gl2lds16(Bg + gmaoff + c * 1024, (char*)Bs[nb] + wvoff + c * 1024);
        }

        // (b) counted wait for P(k) retirement + barrier.
        if (k == 0) {
            if (nv > 2)       asm volatile("s_waitcnt vmcnt(16)\ns_barrier" ::: "memory");
            else if (nv == 2) asm volatile("s_waitcnt vmcnt(8)\ns_barrier" ::: "memory");
            else              asm volatile("s_waitcnt vmcnt(0)\ns_barrier" ::: "memory");
        } else if (k + 2 < nv) {
            asm volatile("s_waitcnt vmcnt(21)\ns_barrier" ::: "memory");
        } else if (k + 1 < nv) {
            asm volatile("s_waitcnt vmcnt(13)\ns_barrier" ::: "memory");
        } else {
            asm volatile("s_waitcnt vmcnt(5)\ns_barrier" ::: "memory");
        }

        // (d) batch-load B fragments, then MFMA burst for BOTH A-sets.
        const char* Bsb = (const char*)Bs[cur];
        f32x4 aA0 = {0.f,0.f,0.f,0.f}, aA1 = {0.f,0.f,0.f,0.f}, aA2 = {0.f,0.f,0.f,0.f};
        f32x4 aB0 = {0.f,0.f,0.f,0.f}, aB1 = {0.f,0.f,0.f,0.f}, aB2 = {0.f,0.f,0.f,0.f};

        if (mt == 0) {
            bf16x8 f0[8], f1[8];
#pragma unroll
            for (int ks = 0; ks < 8; ++ks) {
                int ci = (ks << 2) | quad;
                f0[ks] = *(const bf16x8*)(Bsb + rowB0 * 512 + ((ci ^ keyB0) << 4));
                f1[ks] = *(const bf16x8*)(Bsb + rowB1 * 512 + ((ci ^ keyB1) << 4));
            }
#pragma unroll
            for (int ks = 0; ks < 8; ++ks) {
                aA0 = __builtin_amdgcn_mfma_f32_16x16x32_bf16(afA[ks], f0[ks], aA0, 0, 0, 0);
                aA1 = __builtin_amdgcn_mfma_f32_16x16x32_bf16(afA[ks], f1[ks], aA1, 0, 0, 0);
                aB0 = __builtin_amdgcn_mfma_f32_16x16x32_bf16(afB[ks], f0[ks], aB0, 0, 0, 0);
                aB1 = __builtin_amdgcn_mfma_f32_16x16x32_bf16(afB[ks], f1[ks], aB1, 0, 0, 0);
            }
        } else if (mt == 1) {
            bf16x8 f0[8], f1[8], f2[8];
#pragma unroll
            for (int ks = 0; ks < 8; ++ks) {
                int ci = (ks << 2) | quad;
                f0[ks] = *(const bf16x8*)(Bsb + rowB0 * 512 + ((ci ^ keyB0) << 4));
                f1[ks] = *(const bf16x8*)(Bsb + rowB1 * 512 + ((ci ^ keyB1) << 4));
                f2[ks] = *(const bf16x8*)(Bsb + rowB2 * 512 + ((ci ^ keyB2) << 4));
            }
#pragma unroll
            for (int ks = 0; ks < 8; ++ks) {
                aA0 = __builtin_amdgcn_mfma_f32_16x16x32_bf16(afA[ks], f0[ks], aA0, 0, 0, 0);
                aA1 = __builtin_amdgcn_mfma_f32_16x16x32_bf16(afA[ks], f1[ks], aA1, 0, 0, 0);
                aA2 = __builtin_amdgcn_mfma_f32_16x16x32_bf16(afA[ks], f2[ks], aA2, 0, 0, 0);
                aB0 = __builtin_amdgcn_mfma_f32_16x16x32_bf16(afB[ks], f0[ks], aB0, 0, 0, 0);
                aB1 = __builtin_amdgcn_mfma_f32_16x16x32_bf16(afB[ks], f1[ks], aB1, 0, 0, 0);
                aB2 = __builtin_amdgcn_mfma_f32_16x16x32_bf16(afB[ks], f2[ks], aB2, 0, 0, 0);
            }
        } else {
            bf16x8 f1[8], f2[8];
#pragma unroll
            for (int ks = 0; ks < 8; ++ks) {
                int ci = (ks << 2) | quad;
                f1[ks] = *(const bf16x8*)(Bsb + rowB1 * 512 + ((ci ^ keyB1) << 4));
                f2[ks] = *(const bf16x8*)(Bsb + rowB2 * 512 + ((ci ^ keyB2) << 4));
            }
#pragma unroll
            for (int ks = 0; ks < 8; ++ks) {
                aA1 = __builtin_amdgcn_mfma_f32_16x16x32_bf16(afA[ks], f1[ks], aA1, 0, 0, 0);
                aA2 = __builtin_amdgcn_mfma_f32_16x16x32_bf16(afA[ks], f2[ks], aA2, 0, 0, 0);
                aB1 = __builtin_amdgcn_mfma_f32_16x16x32_bf16(afB[ks], f1[ks], aB1, 0, 0, 0);
                aB2 = __builtin_amdgcn_mfma_f32_16x16x32_bf16(afB[ks], f2[ks], aB2, 0, 0, 0);
            }
        }

        // Scatter both planes (unconditional: in-band cell set is t-invariant,
        // so stale entries are exactly the out-of-range masked ones).
        // C/D: col n = lane&15, row m = quad*4+r. ox = 16*(u+1) + n - (i0+m) - 6.
#pragma unroll
        for (int r = 0; r < 4; ++r) {
            int m = (quad << 2) + r;
            int w = 2 * (i0 + m) + par;
            int oxb = n - i0 - m - 6;
            if (mt != 2) { int ox = 16 + oxb; if (ox >= 0 && ox < NOFF) { sl[0][ox][w] = aA0[r]; sl[1][ox][w] = aB0[r]; } }
            {             int ox = 32 + oxb; if (ox >= 0 && ox < NOFF) { sl[0][ox][w] = aA1[r]; sl[1][ox][w] = aB1[r]; } }
            if (mt != 0) { int ox = 48 + oxb; if (ox >= 0 && ox < NOFF) { sl[0][ox][w] = aA2[r]; sl[1][ox][w] = aB2[r]; } }
        }

        // (e) LDS drain + barrier: slab visible; ring slot reads done so the
        // next iteration's prefetch may overwrite slot (k+3)%3 == cur.
        asm volatile("s_waitcnt lgkmcnt(0)\ns_barrier" ::: "memory");

        // (f) batched slab reads, then plane-masked stores (>=5 per wave,
        // required by the vmcnt ledger; >=1 plane valid per t by construction).
        bool okA = (t >= aLo) & (t < aHi);
        bool okB = (t - 1 >= bLo) & (t - 1 < bHi);
        int outbA = ((b * 441 + t * NOFF) * H_ + hA) * W_;
        int outbB = ((b * 441 + (t - 1) * NOFF) * H_ + hB) * W_;

        float vA[6], vB[6];
#pragma unroll
        for (int j = 0; j < 6; ++j) if (j < jcnt) {
            vA[j] = mj[j] ? slA[slotj[j]] * (1.0f / 256.0f) : 0.0f;
            vB[j] = mj[j] ? slB[slotj[j]] * (1.0f / 256.0f) : 0.0f;
        }
        if (okA) {
#pragma unroll
            for (int j = 0; j < 6; ++j) if (j < jcnt) out[outbA + offj[j]] = vA[j];
        }
        if (okB) {
#pragma unroll
            for (int j = 0; j < 6; ++j) if (j < jcnt) out[outbB + offj[j]] = vB[j];
        }
    }
}

// ---------------------------------------------------------------------------
// Fallback (ws too small): direct fp32, slow but correct.
// ---------------------------------------------------------------------------
__global__ __launch_bounds__(256) void corr_fallback(const float* __restrict__ x1,
                                                     const float* __restrict__ x2,
                                                     float* __restrict__ out) {
    int bid = blockIdx.x;
    int oy = bid % NOFF, h = (bid / NOFF) % H_, b = bid / (NOFF * H_);
    int dy = 2 * oy - 20, h2 = h + dy;
    int outbase = ((b * 441 + oy * NOFF) * H_ + h) * W_;
    for (int idx = threadIdx.x; idx < NOFF * W_; idx += 256) {
        int ox = idx / W_, w = idx % W_;
        float acc = 0.f;
        int w2 = w + 2 * ox - 20;
        if (h2 >= 0 && h2 < H_ && w2 >= 0 && w2 < W_) {
            const float* p1 = x1 + (size_t)b * C_ * H_ * W_ + h * W_ + w;
            const float* p2 = x2 + (size_t)b * C_ * H_ * W_ + h2 * W_ + w2;
            for (int c = 0; c < C_; ++c) acc += p1[c * (H_ * W_)] * p2[c * (H_ * W_)];
        }
        out[outbase + ox * (H_ * W_) + w] = acc * (1.0f / 256.0f);
    }
}

extern "C" void kernel_launch(void* const* d_in, const int* in_sizes, int n_in,
                              void* d_out, int out_size, void* d_ws, size_t ws_size,
                              hipStream_t stream) {
    const float* x1 = (const float*)d_in[0];
    const float* x2 = (const float*)d_in[1];
    float* out = (float*)d_out;

    size_t need = (size_t)2 * X1T_ELEMS * sizeof(unsigned short);  // 37.7 MB
    if (ws_size >= need) {
        unsigned short* ws = (unsigned short*)d_ws;
        prep_kernel<<<B_ * H_ * 2 * 4, 256, 0, stream>>>(x1, x2, ws);
        corr_kernel<<<768, 384, 0, stream>>>(ws, out);
    } else {
        corr_fallback<<<B_ * H_ * NOFF, 256, 0, stream>>>(x1, x2, out);
    }
}